// Round 3
// baseline (330.375 us; speedup 1.0000x reference)
//
#include <hip/hip_runtime.h>
#include <cmath>

// ---------------------------------------------------------------------------
// Classifier pipeline, fp16x2 split-precision MFMA.
// GEMMs: 256x128 tile, 8 waves, BK=32, double-buffered LDS, counted vmcnt,
// XOR slot-swizzle (T2), setprio (T5), XCD swizzle (T1).
//
// d_out byte layout (total 165,412,864 B):
//   feats [8192,1024] f32 @ 0
//   aug   [8192,1024] f32 @ 33,554,432
//   o1    [8192,1000] f32 @ 67,108,864
//   o2    [8192,1000] f32 @ 99,876,864
//   smx   [8192,1000] f32 @ 132,644,864
// Scratch (dead-region hosted, lifetime-checked, same as round 2):
//   fh/fl fp16[8192*2048] @ 67,108,864 / 100,663,296   [conv .. GEMM1]
//   wbh/wbl fp16[1024*2048] @ 134,217,728 / 138,412,032 [conv .. GEMM1]
//   fetsh/fetsl fp16[8192*1024] @ 33,554,432 / 50,331,648 [GEMM1 .. GEMM2]
//   w1h/w1l fp16[1024*1024] @ 142,606,336 / 144,703,488 [conv .. GEMM2]
//   sm1h fp16[8192*1024] @ 99,876,864  [masksm .. GEMM3]
//   cth  fp16[1024*1024] @ 116,654,080 [post-GEMM1 .. GEMM3]
//   w2h  fp16[1024*1024] @ 132,644,864 [post-GEMM1 .. GEMM4]
//   xh   fp16[8192*1024] @ 146,800,640 [rownorm .. GEMM4]
// ---------------------------------------------------------------------------

typedef _Float16 h8 __attribute__((ext_vector_type(8)));
typedef _Float16 h4 __attribute__((ext_vector_type(4)));
typedef float f32x4 __attribute__((ext_vector_type(4)));

__device__ __forceinline__ void gload_lds16(const _Float16* g, _Float16* l) {
    __builtin_amdgcn_global_load_lds(
        (const __attribute__((address_space(1))) void*)g,
        (__attribute__((address_space(3))) void*)l, 16, 0, 0);
}

// MODE 1: C = A@B^T + bias(aux); also write Ch/Cl fp16 split   [fp16x2]
// MODE 2: C = A@B^T, cols<nC                                   [fp16x2]
// MODE 3: C = A@B^T + aux[row,col]                             [fp16x1]
// MODE 4: C = A@B^T * 20, cols<nC                              [fp16x1]
template <int MODE>
__global__ __launch_bounds__(512, 2) void gemm16(
    const _Float16* __restrict__ Ah, const _Float16* __restrict__ Al, int lda,
    const _Float16* __restrict__ Bh, const _Float16* __restrict__ Bl, int ldb,
    int K,
    float* __restrict__ C, int ldc, int nC,
    const float* __restrict__ aux,
    _Float16* __restrict__ Ch, _Float16* __restrict__ Cl)
{
    constexpr bool P2 = (MODE <= 2);
    constexpr int NLOADS = P2 ? 6 : 3;          // gload_lds per wave per K-tile
    // double-buffered tiles: A [256][32] halves, B [128][32] halves
    __shared__ _Float16 sAh[2 * 256 * 32];
    __shared__ _Float16 sBh[2 * 128 * 32];
    __shared__ _Float16 sAl[P2 ? 2 * 256 * 32 : 8];
    __shared__ _Float16 sBl[P2 ? 2 * 128 * 32 : 8];

    const int t = threadIdx.x;
    const int lane = t & 63, wid = t >> 6;
    // T1: bijective XCD swizzle (nwg=256, 8 XCDs, 32/XCD -> 4 M-panels x 8 N)
    const int wg = blockIdx.x;
    const int wgid = (wg & 7) * 32 + (wg >> 3);
    const int row0 = (wgid >> 3) * 256;
    const int col0 = (wgid & 7) * 128;
    const int wr = wid >> 1, wc = wid & 1;      // 4x2 waves -> 64x64 out each
    const int fr = lane & 15;                   // fragment row/col
    // T2 swizzled read k-offset (halves): slot = (lane>>4) ^ (row&3), row&3==lane&3
    const int rks = (((lane >> 4) ^ (lane & 3)) << 3);
    // staging decomposition: 16 rows per 1KB wave-issue; lane -> (row, slot)
    const int srow = lane >> 2;                 // 0..15
    const int sslot = ((lane & 3) ^ (srow & 3)) << 3;  // inverse-swizzled src col (halves)

    f32x4 acc[4][4] = {};
    f32x4 accc[4][4] = {};                      // cross terms (x2048); DCE'd if !P2

    auto stage = [&](int p, int kt) {
        const int kk = kt * 32;
        #pragma unroll
        for (int j = 0; j < 2; ++j) {           // A: 2 wave-issues (i = wid*2+j)
            const int i = wid * 2 + j;
            const int r = i * 16 + srow;
            const size_t ga = (size_t)(row0 + r) * lda + kk + sslot;
            gload_lds16(Ah + ga, &sAh[p * 8192 + i * 512]);
            if constexpr (P2) gload_lds16(Al + ga, &sAl[p * 8192 + i * 512]);
        }
        {                                       // B: 1 wave-issue (i = wid)
            const int r = wid * 16 + srow;
            const size_t gb = (size_t)(col0 + r) * ldb + kk + sslot;
            gload_lds16(Bh + gb, &sBh[p * 4096 + wid * 512]);
            if constexpr (P2) gload_lds16(Bl + gb, &sBl[p * 4096 + wid * 512]);
        }
    };

    auto compute = [&](int p) {
        h8 ah[4], al[4];
        #pragma unroll
        for (int mf = 0; mf < 4; ++mf) {
            const int rr = wr * 64 + mf * 16 + fr;
            ah[mf] = *(const h8*)&sAh[p * 8192 + rr * 32 + rks];
            if constexpr (P2) al[mf] = *(const h8*)&sAl[p * 8192 + rr * 32 + rks];
        }
        #pragma unroll
        for (int half = 0; half < 2; ++half) {  // phase over N-halves of the 4x4 frags
            h8 bh[2], bl[2];
            #pragma unroll
            for (int q = 0; q < 2; ++q) {
                const int cc = wc * 64 + (half * 2 + q) * 16 + fr;
                bh[q] = *(const h8*)&sBh[p * 4096 + cc * 32 + rks];
                if constexpr (P2) bl[q] = *(const h8*)&sBl[p * 4096 + cc * 32 + rks];
            }
            __builtin_amdgcn_s_setprio(1);
            #pragma unroll
            for (int q = 0; q < 2; ++q) {
                const int nf = half * 2 + q;
                #pragma unroll
                for (int mf = 0; mf < 4; ++mf) {
                    acc[mf][nf] = __builtin_amdgcn_mfma_f32_16x16x32_f16(ah[mf], bh[q], acc[mf][nf], 0, 0, 0);
                    if constexpr (P2) {
                        accc[mf][nf] = __builtin_amdgcn_mfma_f32_16x16x32_f16(ah[mf], bl[q], accc[mf][nf], 0, 0, 0);
                        accc[mf][nf] = __builtin_amdgcn_mfma_f32_16x16x32_f16(al[mf], bh[q], accc[mf][nf], 0, 0, 0);
                    }
                }
            }
            __builtin_amdgcn_s_setprio(0);
        }
    };

    const int NT = K >> 5;
    stage(0, 0);
    for (int kt = 0; kt < NT - 1; ++kt) {
        stage((kt + 1) & 1, kt + 1);            // prefetch next tile (stays in flight)
        asm volatile("s_waitcnt vmcnt(%0)" :: "i"(NLOADS) : "memory");  // tile kt ready
        __builtin_amdgcn_s_barrier();
        __builtin_amdgcn_sched_barrier(0);
        compute(kt & 1);
        __builtin_amdgcn_sched_barrier(0);
        __builtin_amdgcn_s_barrier();           // all waves done reading before overwrite
    }
    asm volatile("s_waitcnt vmcnt(0)" ::: "memory");
    __builtin_amdgcn_s_barrier();
    compute((NT - 1) & 1);

    // ---- epilogue (C/D: col=lane&15, row=(lane>>4)*4+j) ----
    #pragma unroll
    for (int mf = 0; mf < 4; ++mf) {
        #pragma unroll
        for (int nf = 0; nf < 4; ++nf) {
            f32x4 v = acc[mf][nf];
            if constexpr (P2) v = v + accc[mf][nf] * (1.0f / 2048.0f);
            const int gcol = col0 + wc * 64 + nf * 16 + fr;
            const int rbase = row0 + wr * 64 + mf * 16 + (lane >> 4) * 4;
            #pragma unroll
            for (int j = 0; j < 4; ++j) {
                const int grow = rbase + j;
                float val = v[j];
                if constexpr (MODE == 1) val += aux[gcol];
                if constexpr (MODE == 3) val += aux[(size_t)grow * 1024 + gcol];
                if constexpr (MODE == 4) val *= 20.0f;
                if (gcol < nC) {
                    C[(size_t)grow * ldc + gcol] = val;
                    if constexpr (MODE == 1) {
                        _Float16 h = (_Float16)val;
                        Ch[(size_t)grow * 1024 + gcol] = h;
                        Cl[(size_t)grow * 1024 + gcol] = (_Float16)((val - (float)h) * 2048.0f);
                    }
                }
            }
        }
    }
}

// fp32 -> fp16 hi/lo split (lo scaled x2048 to stay in fp16 normal range)
__global__ void split_kernel(const float* __restrict__ src,
                             _Float16* __restrict__ hi, _Float16* __restrict__ lo, int n4)
{
    for (int i = blockIdx.x * 256 + threadIdx.x; i < n4; i += gridDim.x * 256) {
        f32x4 v = ((const f32x4*)src)[i];
        h4 h, l;
        #pragma unroll
        for (int j = 0; j < 4; ++j) {
            _Float16 hh = (_Float16)v[j];
            h[j] = hh;
            l[j] = (_Float16)((v[j] - (float)hh) * 2048.0f);
        }
        ((h4*)hi)[i] = h;
        ((h4*)lo)[i] = l;
    }
}

// fp32 [nrows,1024] -> fp16 hi(/lo) padded to [1024,1024] (rows>=nrows zero)
template <bool LO>
__global__ void padsplit_kernel(const float* __restrict__ src,
                                _Float16* __restrict__ hi, _Float16* __restrict__ lo, int nrows)
{
    for (int i = blockIdx.x * 256 + threadIdx.x; i < 1024 * 256; i += gridDim.x * 256) {
        int r = i >> 8;
        f32x4 v = {0.f, 0.f, 0.f, 0.f};
        if (r < nrows) v = ((const f32x4*)src)[i];
        h4 h, l;
        #pragma unroll
        for (int j = 0; j < 4; ++j) {
            _Float16 hh = (_Float16)v[j];
            h[j] = hh;
            if constexpr (LO) l[j] = (_Float16)((v[j] - (float)hh) * 2048.0f);
        }
        ((h4*)hi)[i] = h;
        if constexpr (LO) ((h4*)lo)[i] = l;
    }
}

// cT[n][k] = k<1000 ? fp16(centroid[k][n]) : 0   (LDS-tiled transpose)
__global__ __launch_bounds__(256) void ctrans_kernel(const float* __restrict__ centroid,
                                                     _Float16* __restrict__ cT)
{
    __shared__ float tile[32][33];
    const int t = threadIdx.x;
    const int tx = t & 31, ty = t >> 5;
    const int k0 = blockIdx.y * 32, n0 = blockIdx.x * 32;
    #pragma unroll
    for (int p = 0; p < 4; ++p) {
        int k = k0 + ty + p * 8;
        tile[ty + p * 8][tx] = (k < 1000) ? centroid[(size_t)k * 1024 + n0 + tx] : 0.0f;
    }
    __syncthreads();
    #pragma unroll
    for (int p = 0; p < 4; ++p) {
        int n = n0 + ty + p * 8;
        cT[(size_t)n * 1024 + k0 + tx] = (_Float16)tile[tx][ty + p * 8];
    }
}

// mask_mechanism: argmax -> masked softmax; writes fp16 [8192,1024] (pad zeros)
__global__ __launch_bounds__(256) void masksm_kernel(const float* __restrict__ o1,
                                                     _Float16* __restrict__ sm)
{
    const int row = blockIdx.x;
    const int t = threadIdx.x;
    const float* x = o1 + (size_t)row * 1000;
    _Float16* y = sm + (size_t)row * 1024;

    float bv = -1e30f; int bi = 0;
    for (int c = t; c < 1000; c += 256) {
        float v = x[c];
        if (v > bv) { bv = v; bi = c; }       // first-occurrence argmax
    }
    #pragma unroll
    for (int off = 32; off > 0; off >>= 1) {
        float ov = __shfl_down(bv, off, 64);
        int   oi = __shfl_down(bi, off, 64);
        if (ov > bv || (ov == bv && oi < bi)) { bv = ov; bi = oi; }
    }
    __shared__ float wv[4]; __shared__ int wi[4];
    __shared__ float s_m, s_tot; __shared__ int s_p;
    const int lane = t & 63, wid = t >> 6;
    if (lane == 0) { wv[wid] = bv; wi[wid] = bi; }
    __syncthreads();
    if (t == 0) {
        float mv = wv[0]; int mi = wi[0];
        for (int w = 1; w < 4; ++w)
            if (wv[w] > mv || (wv[w] == mv && wi[w] < mi)) { mv = wv[w]; mi = wi[w]; }
        s_p = mi; s_m = mv;
    }
    __syncthreads();
    const int p = s_p; const float m = s_m;
    if (p >= 500) {
        for (int c = t; c < 1024; c += 256) y[c] = (c == p) ? (_Float16)1.0f : (_Float16)0.0f;
    } else {
        float s = 0.f;
        for (int c = t; c < 1000; c += 256)
            if (c == p || c >= 500) s += expf(x[c] - m);
        #pragma unroll
        for (int off = 32; off > 0; off >>= 1) s += __shfl_down(s, off, 64);
        if (lane == 0) wv[wid] = s;
        __syncthreads();
        if (t == 0) s_tot = wv[0] + wv[1] + wv[2] + wv[3];
        __syncthreads();
        const float inv = 1.0f / s_tot;
        for (int c = t; c < 1024; c += 256) {
            float v = 0.f;
            if (c < 1000 && (c == p || c >= 500)) v = expf(x[c] - m) * inv;
            y[c] = (_Float16)v;
        }
    }
}

// fused: invn = 1/max(||aug_row||,eps); xh = fp16(aug * invn)
__global__ __launch_bounds__(256) void rownorm_x_kernel(const float* __restrict__ aug,
                                                        _Float16* __restrict__ xh)
{
    const int row = blockIdx.x; const int t = threadIdx.x;
    f32x4 v = *((const f32x4*)(aug + (size_t)row * 1024) + t);
    float s = v[0]*v[0] + v[1]*v[1] + v[2]*v[2] + v[3]*v[3];
    #pragma unroll
    for (int off = 32; off > 0; off >>= 1) s += __shfl_down(s, off, 64);
    __shared__ float ws4[4]; __shared__ float s_inv;
    const int lane = t & 63, wid = t >> 6;
    if (lane == 0) ws4[wid] = s;
    __syncthreads();
    if (t == 0) {
        float tot = ws4[0] + ws4[1] + ws4[2] + ws4[3];
        s_inv = 1.0f / fmaxf(sqrtf(tot), 1e-12f);
    }
    __syncthreads();
    const float inv = s_inv;
    h4 h;
    #pragma unroll
    for (int j = 0; j < 4; ++j) h[j] = (_Float16)(v[j] * inv);
    *((h4*)(xh + (size_t)row * 1024) + t) = h;
}

// plain row softmax over 1000
__global__ __launch_bounds__(256) void softmax2_kernel(const float* __restrict__ o2,
                                                       float* __restrict__ out)
{
    const int row = blockIdx.x; const int t = threadIdx.x;
    const float* x = o2 + (size_t)row * 1000;
    float* y = out + (size_t)row * 1000;
    float m = -1e30f;
    for (int c = t; c < 1000; c += 256) m = fmaxf(m, x[c]);
    #pragma unroll
    for (int off = 32; off > 0; off >>= 1) m = fmaxf(m, __shfl_down(m, off, 64));
    __shared__ float sm4[4]; __shared__ float s_m, s_s;
    const int lane = t & 63, wid = t >> 6;
    if (lane == 0) sm4[wid] = m;
    __syncthreads();
    if (t == 0) s_m = fmaxf(fmaxf(sm4[0], sm4[1]), fmaxf(sm4[2], sm4[3]));
    __syncthreads();
    m = s_m;
    float s = 0.f;
    for (int c = t; c < 1000; c += 256) s += expf(x[c] - m);
    #pragma unroll
    for (int off = 32; off > 0; off >>= 1) s += __shfl_down(s, off, 64);
    if (lane == 0) sm4[wid] = s;
    __syncthreads();
    if (t == 0) s_s = sm4[0] + sm4[1] + sm4[2] + sm4[3];
    __syncthreads();
    const float inv = 1.0f / s_s;
    for (int c = t; c < 1000; c += 256) y[c] = expf(x[c] - m) * inv;
}

extern "C" void kernel_launch(void* const* d_in, const int* in_sizes, int n_in,
                              void* d_out, int out_size, void* d_ws, size_t ws_size,
                              hipStream_t stream)
{
    const float* features = (const float*)d_in[0];  // [8192,2048]
    const float* W_b      = (const float*)d_in[1];  // [1024,2048]
    const float* b_b      = (const float*)d_in[2];  // [1024]
    const float* W1       = (const float*)d_in[3];  // [1000,1024]
    const float* W2       = (const float*)d_in[4];  // [1000,1024]
    const float* centroid = (const float*)d_in[5];  // [1000,1024]

    char* base = (char*)d_out;
    float* feats = (float*)(base);
    float* aug   = (float*)(base + 33554432);
    float* o1    = (float*)(base + 67108864);
    float* o2    = (float*)(base + 99876864);
    float* smx   = (float*)(base + 132644864);

    _Float16* fh    = (_Float16*)(base + 67108864);
    _Float16* fl    = (_Float16*)(base + 100663296);
    _Float16* wbh   = (_Float16*)(base + 134217728);
    _Float16* wbl   = (_Float16*)(base + 138412032);
    _Float16* fetsh = (_Float16*)(base + 33554432);
    _Float16* fetsl = (_Float16*)(base + 50331648);
    _Float16* w1h   = (_Float16*)(base + 142606336);
    _Float16* w1l   = (_Float16*)(base + 144703488);
    _Float16* sm1h  = (_Float16*)(base + 99876864);
    _Float16* cth   = (_Float16*)(base + 116654080);
    _Float16* w2h   = (_Float16*)(base + 132644864);
    _Float16* xh    = (_Float16*)(base + 146800640);

    // conversions with no GEMM dependency
    split_kernel<<<2048, 256, 0, stream>>>(features, fh, fl, 4194304);
    split_kernel<<<2048, 256, 0, stream>>>(W_b, wbh, wbl, 524288);
    padsplit_kernel<true><<<1024, 256, 0, stream>>>(W1, w1h, w1l, 1000);

    // GEMM1: feats = F@W_b^T + b_b (fp16x2); epilogue also emits feats hi/lo
    gemm16<1><<<256, 512, 0, stream>>>(fh, fl, 2048, wbh, wbl, 2048, 2048,
                                       feats, 1024, 1024, b_b, fetsh, fetsl);

    // these regions overlap fh/fl/wbh (dead after GEMM1) -> launch after GEMM1
    ctrans_kernel<<<dim3(32, 32), 256, 0, stream>>>(centroid, cth);
    padsplit_kernel<false><<<1024, 256, 0, stream>>>(W2, w2h, nullptr, 1000);

    // GEMM2: o1 = feats@W1^T (fp16x2, argmax-critical)
    gemm16<2><<<256, 512, 0, stream>>>(fetsh, fetsl, 1024, w1h, w1l, 1024, 1024,
                                       o1, 1000, 1000, nullptr, nullptr, nullptr);

    masksm_kernel<<<8192, 256, 0, stream>>>(o1, sm1h);

    // GEMM3: aug = sm1@centroid + feats (fp16x1)
    gemm16<3><<<256, 512, 0, stream>>>(sm1h, nullptr, 1024, cth, nullptr, 1024, 1024,
                                       aug, 1024, 1024, feats, nullptr, nullptr);

    rownorm_x_kernel<<<8192, 256, 0, stream>>>(aug, xh);

    // GEMM4: o2 = x@W2^T * 20 (fp16x1)
    gemm16<4><<<256, 512, 0, stream>>>(xh, nullptr, 1024, w2h, nullptr, 1024, 1024,
                                       o2, 1000, 1000, nullptr, nullptr, nullptr);

    softmax2_kernel<<<8192, 256, 0, stream>>>(o2, smx);
}